// Round 3
// baseline (1138.453 us; speedup 1.0000x reference)
//
#include <hip/hip_runtime.h>
#include <math.h>

#define BB 64
#define CC 512
#define HW 784
#define DD 512
#define GR 512
#define KK 20

typedef __bf16 bf16x8 __attribute__((ext_vector_type(8)));
typedef float f32x16 __attribute__((ext_vector_type(16)));

// ---------------------------------------------------------------------------
// Fused Gram + scores: per 128x128 G-tile (bf16 MFMA, hi/lo compensated),
// contract in-register against U[cd][20] and emit per-block partial scores.
// No G materialization. grid (10 tile-pairs, 64 b), 512 thr, 128 KB dyn LDS.
// ---------------------------------------------------------------------------
__global__ __launch_bounds__(512) void gram_fused(const float* __restrict__ X,
                                                  const float* __restrict__ U,
                                                  float* __restrict__ Pout) {
  extern __shared__ unsigned short lds[];
  unsigned short* __restrict__ Ahi = lds;           // [128][128]
  unsigned short* __restrict__ Alo = lds + 16384;
  unsigned short* __restrict__ Bhi = lds + 32768;
  unsigned short* __restrict__ Blo = lds + 49152;

  const int b = blockIdx.y;
  int lin = blockIdx.x;
  int i = 0;
  while (lin >= 4 - i) { lin -= 4 - i; ++i; }
  const int j = i + lin;  // i <= j
  const bool diag = (i == j);

  const float* __restrict__ xb = X + (size_t)b * (CC * HW);
  const int tid = threadIdx.x;
  const int w = tid >> 6, l = tid & 63;
  const int wr = w >> 1;  // 0..3 row block (32 rows)
  const int wc = w & 1;   // 0..1 col block (64 cols)

  f32x16 acc0 = {};
  f32x16 acc1 = {};

  for (int it = 0; it < 7; ++it) {
    const int k0 = it * 112;
    __syncthreads();
#pragma unroll
    for (int q = 0; q < 7; ++q) {
      const int f = tid + q * 512;
      const int r = f / 28, pos = f % 28;
      const int chunk = pos >> 1;
      const int soff = r * 128 + (((chunk ^ (r & 7)) << 3) | ((pos & 1) << 2));
#pragma unroll
      for (int pnl = 0; pnl < 2; ++pnl) {
        if (pnl && diag) break;
        const int rowbase = (pnl ? j : i) * 128;
        float4 v = *(const float4*)(xb + (size_t)(rowbase + r) * HW + k0 + pos * 4);
        unsigned int u0 = __builtin_bit_cast(unsigned int, v.x);
        unsigned int u1 = __builtin_bit_cast(unsigned int, v.y);
        unsigned int u2 = __builtin_bit_cast(unsigned int, v.z);
        unsigned int u3 = __builtin_bit_cast(unsigned int, v.w);
        float h0 = __builtin_bit_cast(float, u0 & 0xFFFF0000u);
        float h1 = __builtin_bit_cast(float, u1 & 0xFFFF0000u);
        float h2 = __builtin_bit_cast(float, u2 & 0xFFFF0000u);
        float h3 = __builtin_bit_cast(float, u3 & 0xFFFF0000u);
        unsigned int hp0 = (u0 >> 16) | (u1 & 0xFFFF0000u);
        unsigned int hp1 = (u2 >> 16) | (u3 & 0xFFFF0000u);
        unsigned int l0 = __builtin_bit_cast(unsigned int, v.x - h0) >> 16;
        unsigned int l1 = __builtin_bit_cast(unsigned int, v.y - h1) >> 16;
        unsigned int l2 = __builtin_bit_cast(unsigned int, v.z - h2) >> 16;
        unsigned int l3 = __builtin_bit_cast(unsigned int, v.w - h3) >> 16;
        unsigned int lp0 = l0 | (l1 << 16);
        unsigned int lp1 = l2 | (l3 << 16);
        unsigned short* hp = pnl ? Bhi : Ahi;
        unsigned short* lp = pnl ? Blo : Alo;
        *(uint2*)(hp + soff) = make_uint2(hp0, hp1);
        *(uint2*)(lp + soff) = make_uint2(lp0, lp1);
      }
    }
    __syncthreads();
    const unsigned short* __restrict__ bhiP = diag ? Ahi : Bhi;
    const unsigned short* __restrict__ bloP = diag ? Alo : Blo;
#pragma unroll
    for (int ks = 0; ks < 7; ++ks) {
      const int chunk = ks * 2 + (l >> 5);
      const int ar = wr * 32 + (l & 31);
      const int aoff = ar * 128 + ((chunk ^ (ar & 7)) << 3);
      bf16x8 ah = *(const bf16x8*)(Ahi + aoff);
      bf16x8 al = *(const bf16x8*)(Alo + aoff);
      const int br0 = wc * 64 + (l & 31);
      const int boff0 = br0 * 128 + ((chunk ^ (br0 & 7)) << 3);
      const int br1 = br0 + 32;
      const int boff1 = br1 * 128 + ((chunk ^ (br1 & 7)) << 3);
      bf16x8 bh0 = *(const bf16x8*)(bhiP + boff0);
      bf16x8 bl0 = *(const bf16x8*)(bloP + boff0);
      bf16x8 bh1 = *(const bf16x8*)(bhiP + boff1);
      bf16x8 bl1 = *(const bf16x8*)(bloP + boff1);
      acc0 = __builtin_amdgcn_mfma_f32_32x32x16_bf16(ah, bh0, acc0, 0, 0, 0);
      acc0 = __builtin_amdgcn_mfma_f32_32x32x16_bf16(ah, bl0, acc0, 0, 0, 0);
      acc0 = __builtin_amdgcn_mfma_f32_32x32x16_bf16(al, bh0, acc0, 0, 0, 0);
      acc1 = __builtin_amdgcn_mfma_f32_32x32x16_bf16(ah, bh1, acc1, 0, 0, 0);
      acc1 = __builtin_amdgcn_mfma_f32_32x32x16_bf16(ah, bl1, acc1, 0, 0, 0);
      acc1 = __builtin_amdgcn_mfma_f32_32x32x16_bf16(al, bh1, acc1, 0, 0, 0);
    }
  }

  // ---- epilogue: contract G-tile against U, emit partial scores ----
  float p[20];
#pragma unroll
  for (int k = 0; k < 20; ++k) p[k] = 0.f;
  const int rowbase = i * 128 + wr * 32 + 4 * (l >> 5);
  const int colbase = j * 128 + wc * 64 + (l & 31);
#pragma unroll
  for (int n = 0; n < 2; ++n) {
    const f32x16 a = n ? acc1 : acc0;
#pragma unroll
    for (int reg = 0; reg < 16; ++reg) {
      const int row = rowbase + (reg & 3) + 8 * (reg >> 2);
      const int col = colbase + n * 32;
      const float v = a[reg];
      const float4* __restrict__ uf =
          (const float4*)(U + ((size_t)row * CC + col) * KK);
#pragma unroll
      for (int q5 = 0; q5 < 5; ++q5) {
        float4 u4 = uf[q5];
        p[q5 * 4 + 0] = fmaf(v, u4.x, p[q5 * 4 + 0]);
        p[q5 * 4 + 1] = fmaf(v, u4.y, p[q5 * 4 + 1]);
        p[q5 * 4 + 2] = fmaf(v, u4.z, p[q5 * 4 + 2]);
        p[q5 * 4 + 3] = fmaf(v, u4.w, p[q5 * 4 + 3]);
      }
      if (!diag) {
        const float4* __restrict__ um =
            (const float4*)(U + ((size_t)col * CC + row) * KK);
#pragma unroll
        for (int q5 = 0; q5 < 5; ++q5) {
          float4 u4 = um[q5];
          p[q5 * 4 + 0] = fmaf(v, u4.x, p[q5 * 4 + 0]);
          p[q5 * 4 + 1] = fmaf(v, u4.y, p[q5 * 4 + 1]);
          p[q5 * 4 + 2] = fmaf(v, u4.z, p[q5 * 4 + 2]);
          p[q5 * 4 + 3] = fmaf(v, u4.w, p[q5 * 4 + 3]);
        }
      }
    }
  }
  // fixed-order wave reduce, then LDS reduce over 8 waves
#pragma unroll
  for (int k = 0; k < 20; ++k) {
#pragma unroll
    for (int o = 32; o; o >>= 1) p[k] += __shfl_xor(p[k], o);
  }
  __shared__ float wred[8][20];
  if (l == 0) {
#pragma unroll
    for (int k = 0; k < 20; ++k) wred[w][k] = p[k];
  }
  __syncthreads();
  if (tid < 20) {
    float s = 0.f;
#pragma unroll
    for (int ww = 0; ww < 8; ++ww) s += wred[ww][tid];
    Pout[(size_t)(blockIdx.x * 64 + b) * KK + tid] = s;
  }
}

// ---------------------------------------------------------------------------
// U kernel v2: U[cd][k] = sum_r W[cd][r]*C[k][r].  BK=32 (128 B per row-visit)
// -> each 128 B line of gram_w read exactly once. grid 1024, block 256.
// ---------------------------------------------------------------------------
__global__ __launch_bounds__(256) void u_kernel2(const float* __restrict__ W,
                                                 const float* __restrict__ C,
                                                 float* __restrict__ U) {
  __shared__ float Ws[256][36];
  __shared__ float Ct[20][36];

  const int tid = threadIdx.x;
  const int rt = tid >> 2, kq = tid & 3;
  const size_t row0 = (size_t)blockIdx.x << 8;

  float acc[4][5] = {};

  for (int k0 = 0; k0 < GR; k0 += 32) {
    __syncthreads();
#pragma unroll
    for (int q = 0; q < 8; ++q) {
      const int row = q * 32 + (tid >> 3);
      const int col = (tid & 7) * 4;
      float4 w4 = *(const float4*)(W + (row0 + row) * GR + k0 + col);
      *(float4*)&Ws[row][col] = w4;
    }
    if (tid < 160) {
      const int k = tid >> 3, pp = tid & 7;
      *(float4*)&Ct[k][pp * 4] = *(const float4*)(C + k * GR + k0 + pp * 4);
    }
    __syncthreads();
#pragma unroll
    for (int kk4 = 0; kk4 < 8; ++kk4) {
      float4 wv[4];
#pragma unroll
      for (int u = 0; u < 4; ++u)
        wv[u] = *(const float4*)&Ws[rt + u * 64][kk4 * 4];
#pragma unroll
      for (int q = 0; q < 5; ++q) {
        float4 c4 = *(const float4*)&Ct[kq * 5 + q][kk4 * 4];
#pragma unroll
        for (int u = 0; u < 4; ++u) {
          acc[u][q] = fmaf(wv[u].x, c4.x, acc[u][q]);
          acc[u][q] = fmaf(wv[u].y, c4.y, acc[u][q]);
          acc[u][q] = fmaf(wv[u].z, c4.z, acc[u][q]);
          acc[u][q] = fmaf(wv[u].w, c4.w, acc[u][q]);
        }
      }
    }
  }
#pragma unroll
  for (int u = 0; u < 4; ++u)
#pragma unroll
    for (int q = 0; q < 5; ++q)
      U[(row0 + rt + u * 64) * KK + kq * 5 + q] = acc[u][q];
}

// offs[k] = ||c_k||^2 - 2*dot(gram_b, c_k).  grid 20, block 64.
__global__ void offs_k(const float* __restrict__ C, const float* __restrict__ gb,
                       float* __restrict__ offs) {
  int k = blockIdx.x, t = threadIdx.x;
  float a = 0.f;
  for (int r = t; r < GR; r += 64) {
    float c = C[k * GR + r];
    a += c * c - 2.0f * gb[r] * c;
  }
#pragma unroll
  for (int o = 32; o; o >>= 1) a += __shfl_down(a, o);
  if (t == 0) offs[k] = a;
}

// argmin over k, then concat(x_main, centers[idx]) -> x_fused. grid 64, blk 256.
__global__ __launch_bounds__(256) void argmin_concat_k(
    const float* __restrict__ P, const float* __restrict__ offs,
    const float* __restrict__ xm, const float* __restrict__ C,
    float* __restrict__ xf) {
  const int b = blockIdx.x, t = threadIdx.x;
  __shared__ float vals[20];
  __shared__ int bestIdx;
  if (t < 20) {
    float s = 0.f;
#pragma unroll
    for (int pr = 0; pr < 10; ++pr) s += P[(size_t)(pr * 64 + b) * KK + t];
    vals[t] = offs[t] - 2.0f * (1.0f / (float)HW) * s;
  }
  __syncthreads();
  if (t == 0) {
    float best = vals[0];
    int bi = 0;
    for (int k = 1; k < 20; ++k)
      if (vals[k] < best) { best = vals[k]; bi = k; }
    bestIdx = bi;
  }
  __syncthreads();
  const int bi = bestIdx;
#pragma unroll
  for (int q = 0; q < 4; ++q) {
    const int i = q * 256 + t;
    xf[(size_t)b * 1024 + i] =
        (i < 512) ? xm[(size_t)b * 512 + i] : C[(size_t)bi * 512 + (i - 512)];
  }
}

// ---------------------------------------------------------------------------
// Linear: out = post(act(opt_LN(A) @ W + bias)).  M=64 rows.
// grid (ceil(N/64), 4), block (64,4). Stages K-tiles of 512 fully in LDS.
// ACT: 0 none, 1 relu, 2 gelu, 3 sigmoid.  LN requires K==512.
// ---------------------------------------------------------------------------
template <int ACT, bool LN, bool GATE, bool RES>
__global__ __launch_bounds__(256) void lin_k(
    const float* __restrict__ A, const float* __restrict__ W,
    const float* __restrict__ bias, const float* __restrict__ lng,
    const float* __restrict__ lnb, const float* __restrict__ gate,
    const float* __restrict__ res, float* __restrict__ out, int N, int K) {
  __shared__ float As[16][520];
  const int tx = threadIdx.x, ty = threadIdx.y;
  const int tid = ty * 64 + tx;
  const int n = blockIdx.x * 64 + tx;
  const int r0 = blockIdx.y * 16;
  float acc[4] = {0.f, 0.f, 0.f, 0.f};

  for (int k0 = 0; k0 < K; k0 += 512) {
    const int KT = (K - k0 < 512) ? (K - k0) : 512;
    __syncthreads();
    const int sr = tid >> 4, scq = tid & 15;
    float lsum = 0.f, lss = 0.f;
#pragma unroll
    for (int q = 0; q < 8; ++q) {
      const int c = scq * 4 + q * 64;
      if (c < KT) {
        float4 v = *(const float4*)(A + (size_t)(r0 + sr) * K + k0 + c);
        *(float4*)&As[sr][c] = v;
        if (LN) {
          lsum += v.x + v.y + v.z + v.w;
          lss += v.x * v.x + v.y * v.y + v.z * v.z + v.w * v.w;
        }
      }
    }
    if (LN) {
#pragma unroll
      for (int o = 1; o < 16; o <<= 1) {
        lsum += __shfl_xor(lsum, o);
        lss += __shfl_xor(lss, o);
      }
      const float m = lsum * (1.0f / 512.0f);
      const float inv = rsqrtf(lss * (1.0f / 512.0f) - m * m + 1e-5f);
#pragma unroll
      for (int q = 0; q < 8; ++q) {
        const int c = scq * 4 + q * 64;
        float4 v = *(float4*)&As[sr][c];
        float4 g4 = *(const float4*)(lng + c);
        float4 b4 = *(const float4*)(lnb + c);
        v.x = (v.x - m) * inv * g4.x + b4.x;
        v.y = (v.y - m) * inv * g4.y + b4.y;
        v.z = (v.z - m) * inv * g4.z + b4.z;
        v.w = (v.w - m) * inv * g4.w + b4.w;
        *(float4*)&As[sr][c] = v;
      }
    }
    __syncthreads();
    if (n < N) {
      for (int kk = 0; kk < KT; kk += 4) {
        const float w0 = W[(size_t)(k0 + kk + 0) * N + n];
        const float w1 = W[(size_t)(k0 + kk + 1) * N + n];
        const float w2 = W[(size_t)(k0 + kk + 2) * N + n];
        const float w3 = W[(size_t)(k0 + kk + 3) * N + n];
#pragma unroll
        for (int u = 0; u < 4; ++u) {
          float4 a4 = *(const float4*)&As[ty * 4 + u][kk];
          acc[u] = fmaf(a4.x, w0, acc[u]);
          acc[u] = fmaf(a4.y, w1, acc[u]);
          acc[u] = fmaf(a4.z, w2, acc[u]);
          acc[u] = fmaf(a4.w, w3, acc[u]);
        }
      }
    }
  }
  if (n < N) {
    const float bv = bias[n];
#pragma unroll
    for (int u = 0; u < 4; ++u) {
      const int r = r0 + ty * 4 + u;
      float v = acc[u] + bv;
      if (ACT == 1) v = v > 0.f ? v : 0.f;
      else if (ACT == 2) v = 0.5f * v * (1.0f + erff(v * 0.70710678118654752f));
      else if (ACT == 3) v = 1.0f / (1.0f + expf(-v));
      if (GATE) v *= gate[(size_t)r * N + n];
      if (RES) v += res[(size_t)r * N + n];
      out[(size_t)r * N + n] = v;
    }
  }
}

// ---------------------------------------------------------------------------
extern "C" void kernel_launch(void* const* d_in, const int* in_sizes, int n_in,
                              void* d_out, int out_size, void* d_ws,
                              size_t ws_size, hipStream_t stream) {
  const float* x_embed = (const float*)d_in[0];
  const float* x_image = (const float*)d_in[1];
  const float* attn_w1 = (const float*)d_in[2];
  const float* attn_b1 = (const float*)d_in[3];
  const float* attn_w2 = (const float*)d_in[4];
  const float* attn_b2 = (const float*)d_in[5];
  const float* ln_ff_g = (const float*)d_in[6];
  const float* ln_ff_b = (const float*)d_in[7];
  const float* ff_w1 = (const float*)d_in[8];
  const float* ff_b1 = (const float*)d_in[9];
  const float* ff_w2 = (const float*)d_in[10];
  const float* ff_b2 = (const float*)d_in[11];
  const float* gram_w = (const float*)d_in[12];
  const float* gram_b = (const float*)d_in[13];
  const float* centers = (const float*)d_in[14];
  const float* gm_w = (const float*)d_in[15];
  const float* gm_b = (const float*)d_in[16];
  const float* ln1_g = (const float*)d_in[17];
  const float* ln1_b = (const float*)d_in[18];
  const float* m1_w = (const float*)d_in[19];
  const float* m1_b = (const float*)d_in[20];
  const float* m2_w1 = (const float*)d_in[21];
  const float* m2_b1 = (const float*)d_in[22];
  const float* m2_w2 = (const float*)d_in[23];
  const float* m2_b2 = (const float*)d_in[24];
  const float* out_w = (const float*)d_in[25];
  const float* out_b = (const float*)d_in[26];

  float* ws = (float*)d_ws;
  size_t off = 0;
  auto alloc = [&](size_t nelem) {
    float* p = ws + off;
    off += (nelem + 63) & ~(size_t)63;
    return p;
  };
  float* U = alloc((size_t)CC * CC * KK);   // 21 MB
  float* P = alloc((size_t)640 * KK);
  float* offs = alloc(64);
  float* h1 = alloc(BB * DD);
  float* x_attn = alloc(BB * DD);
  float* f1 = alloc(BB * 4 * DD);
  float* x_main = alloc(BB * DD);
  float* x_fused = alloc(BB * (DD + GR));
  float* x_h = alloc(BB * DD);
  float* hh = alloc(BB * DD);
  float* h2 = alloc(BB * DD);
  float* h3 = alloc(BB * (DD / 2));

  dim3 blk(64, 4);

  // --- gram branch ---
  offs_k<<<20, 64, 0, stream>>>(centers, gram_b, offs);
  u_kernel2<<<1024, 256, 0, stream>>>(gram_w, centers, U);
  hipFuncSetAttribute(reinterpret_cast<const void*>(gram_fused),
                      hipFuncAttributeMaxDynamicSharedMemorySize, 131072);
  gram_fused<<<dim3(10, BB), 512, 131072, stream>>>(x_image, U, P);

  // --- MLP branch ---
  lin_k<1, false, false, false><<<dim3(8, 4), blk, 0, stream>>>(
      x_embed, attn_w1, attn_b1, nullptr, nullptr, nullptr, nullptr, h1, 512, 512);
  lin_k<3, false, true, false><<<dim3(8, 4), blk, 0, stream>>>(
      h1, attn_w2, attn_b2, nullptr, nullptr, x_embed, nullptr, x_attn, 512, 512);
  lin_k<2, true, false, false><<<dim3(32, 4), blk, 0, stream>>>(
      x_attn, ff_w1, ff_b1, ln_ff_g, ln_ff_b, nullptr, nullptr, f1, 2048, 512);
  lin_k<0, false, false, true><<<dim3(8, 4), blk, 0, stream>>>(
      f1, ff_w2, ff_b2, nullptr, nullptr, nullptr, x_attn, x_main, 512, 2048);

  // --- fuse ---
  argmin_concat_k<<<64, 256, 0, stream>>>(P, offs, x_main, centers, x_fused);
  lin_k<2, false, false, false><<<dim3(8, 4), blk, 0, stream>>>(
      x_fused, gm_w, gm_b, nullptr, nullptr, nullptr, nullptr, x_h, 512, 1024);
  lin_k<2, true, false, true><<<dim3(8, 4), blk, 0, stream>>>(
      x_h, m1_w, m1_b, ln1_g, ln1_b, nullptr, x_h, hh, 512, 512);
  lin_k<2, false, false, false><<<dim3(8, 4), blk, 0, stream>>>(
      hh, m2_w1, m2_b1, nullptr, nullptr, nullptr, nullptr, h2, 512, 512);
  lin_k<2, false, false, false><<<dim3(4, 4), blk, 0, stream>>>(
      h2, m2_w2, m2_b2, nullptr, nullptr, nullptr, nullptr, h3, 256, 512);
  lin_k<0, false, false, false><<<dim3(1, 4), blk, 0, stream>>>(
      h3, out_w, out_b, nullptr, nullptr, nullptr, nullptr, (float*)d_out, 10, 256);
}

// Round 4
// 1051.154 us; speedup vs baseline: 1.0831x; 1.0831x over previous
//
#include <hip/hip_runtime.h>
#include <math.h>

#define BB 64
#define CC 512
#define HW 784
#define DD 512
#define GR 512
#define KK 20

typedef __bf16 bf16x8 __attribute__((ext_vector_type(8)));
typedef float f32x16 __attribute__((ext_vector_type(16)));

__device__ inline unsigned short bf16rtn(float f) {
  unsigned int u = __builtin_bit_cast(unsigned int, f);
  unsigned int r = (u + 0x7FFFu + ((u >> 16) & 1u)) >> 16;
  return (unsigned short)r;
}

// ---------------------------------------------------------------------------
// Gram: G[b] = xf[b] @ xf[b]^T / 784, bf16 MFMA (plain RTN, no compensation).
// 128x128 tiles, upper-tri pairs mirror-stored. 1D grid 640, XCD-aware decode
// (8 batches per XCD -> X panels L2-resident). 512 thr, 64 KB dyn LDS,
// 2 blocks/CU. BK=112 (7 iters x 7 k-steps).
// ---------------------------------------------------------------------------
__global__ __launch_bounds__(512) void gram_mfma(const float* __restrict__ X,
                                                 float* __restrict__ G) {
  extern __shared__ unsigned short lds[];
  unsigned short* __restrict__ Apl = lds;           // [128][128] (112 used)
  unsigned short* __restrict__ Bpl = lds + 16384;

  const int bid = blockIdx.x;          // 640 = 8 xcd * 8 b * 10 pairs
  const int xcd = bid & 7;
  const int kslot = bid >> 3;          // 0..79
  const int b = xcd * 8 + kslot / 10;
  int lin = kslot % 10;
  int i = 0;
  while (lin >= 4 - i) { lin -= 4 - i; ++i; }
  const int j = i + lin;  // i <= j
  const bool diag = (i == j);

  const float* __restrict__ xb = X + (size_t)b * (CC * HW);
  const int tid = threadIdx.x;
  const int w = tid >> 6, l = tid & 63;
  const int wr = w >> 1;  // 0..3: 32-row block
  const int wc = w & 1;   // 0..1: 64-col block

  f32x16 acc0 = {};
  f32x16 acc1 = {};

  const int sr = tid >> 2;        // 0..127 staging row
  const int lane4 = tid & 3;

  for (int it = 0; it < 7; ++it) {
    const int k0 = it * 112;
    __syncthreads();
#pragma unroll
    for (int q = 0; q < 7; ++q) {
      const int pos = lane4 + q * 4;          // float4 index 0..27
      const int chunk = pos >> 1;
      const int soff =
          sr * 128 + (((chunk ^ (sr & 7)) << 3) | ((pos & 1) << 2));
#pragma unroll
      for (int pnl = 0; pnl < 2; ++pnl) {
        if (pnl && diag) break;
        const int rowbase = (pnl ? j : i) * 128;
        float4 v =
            *(const float4*)(xb + (size_t)(rowbase + sr) * HW + k0 + pos * 4);
        unsigned int p0 = bf16rtn(v.x) | ((unsigned int)bf16rtn(v.y) << 16);
        unsigned int p1 = bf16rtn(v.z) | ((unsigned int)bf16rtn(v.w) << 16);
        *(uint2*)((pnl ? Bpl : Apl) + soff) = make_uint2(p0, p1);
      }
    }
    __syncthreads();
    const unsigned short* __restrict__ bP = diag ? Apl : Bpl;
#pragma unroll
    for (int ks = 0; ks < 7; ++ks) {
      const int chunk = ks * 2 + (l >> 5);
      const int ar = wr * 32 + (l & 31);
      bf16x8 a = *(const bf16x8*)(Apl + ar * 128 + ((chunk ^ (ar & 7)) << 3));
      const int br0 = wc * 64 + (l & 31);
      const int br1 = br0 + 32;
      bf16x8 b0 = *(const bf16x8*)(bP + br0 * 128 + ((chunk ^ (br0 & 7)) << 3));
      bf16x8 b1 = *(const bf16x8*)(bP + br1 * 128 + ((chunk ^ (br1 & 7)) << 3));
      acc0 = __builtin_amdgcn_mfma_f32_32x32x16_bf16(a, b0, acc0, 0, 0, 0);
      acc1 = __builtin_amdgcn_mfma_f32_32x32x16_bf16(a, b1, acc1, 0, 0, 0);
    }
  }

  const float sc = 1.0f / (float)HW;
  float* __restrict__ gb = G + (size_t)b * (CC * CC);
  const int rowbase = i * 128 + wr * 32 + 4 * (l >> 5);
  const int colbase = j * 128 + wc * 64 + (l & 31);
#pragma unroll
  for (int n = 0; n < 2; ++n) {
    const f32x16 a = n ? acc1 : acc0;
#pragma unroll
    for (int reg = 0; reg < 16; ++reg) {
      const int row = rowbase + (reg & 3) + 8 * (reg >> 2);
      const int col = colbase + n * 32;
      const float v = a[reg] * sc;
      gb[(size_t)row * CC + col] = v;
      if (!diag) gb[(size_t)col * CC + row] = v;
    }
  }
}

// ---------------------------------------------------------------------------
// U = W[262144,512] @ C[20,512]^T -> U[262144,20], bf16 MFMA.
// grid 2048 x 256 thr (4 waves, 32 rows each). Frag-ordered LDS staging:
// all ds_read_b128 fully coalesced & conflict-free. 48 KB LDS -> 3 blk/CU.
// Memory-bound: streams W (537 MB) exactly once.
// ---------------------------------------------------------------------------
__global__ __launch_bounds__(256) void u_mfma(const float* __restrict__ Wg,
                                              const float* __restrict__ C,
                                              float* __restrict__ U) {
  __shared__ unsigned short Cf[32 * 64 * 8];  // [s][lane][8] = 32 KB
  __shared__ unsigned short Wf[16 * 64 * 8];  // [s4*4+wave][lane][8] = 16 KB

  const int tid = threadIdx.x;
  const int w = tid >> 6, l = tid & 63;
  const size_t row0 = (size_t)blockIdx.x * 128;

  // stage C fragments once (frag order: slot (s, lane))
#pragma unroll
  for (int e = 0; e < 8; ++e) {
    const int idx = tid * 8 + e;  // 0..2047
    const int s = idx >> 6, ln = idx & 63;
    const int col = ln & 31;
    const int kbase = s * 16 + (ln >> 5) * 8;
    unsigned int pk[4] = {0u, 0u, 0u, 0u};
    if (col < KK) {
      const float* src = C + (size_t)col * GR + kbase;
#pragma unroll
      for (int jj = 0; jj < 4; ++jj)
        pk[jj] = bf16rtn(src[jj * 2]) |
                 ((unsigned int)bf16rtn(src[jj * 2 + 1]) << 16);
    }
    *(uint4*)(Cf + idx * 8) = make_uint4(pk[0], pk[1], pk[2], pk[3]);
  }

  f32x16 acc = {};

  for (int c = 0; c < 8; ++c) {
    __syncthreads();
    // stage 128 rows x 64 k of W as bf16 fragments
#pragma unroll
    for (int q = 0; q < 8; ++q) {
      const int flat = q * 256 + tid;        // float4 slots 0..2047
      const int row = flat >> 4, pos = flat & 15;
      float4 v = *(const float4*)(Wg + (row0 + row) * GR + c * 64 + pos * 4);
      const int s4 = pos >> 2;
      const int lane = (row & 31) + ((pos >> 1) & 1) * 32;
      const int jj = (pos & 1) * 4;
      const int wv = row >> 5;
      unsigned int p0 = bf16rtn(v.x) | ((unsigned int)bf16rtn(v.y) << 16);
      unsigned int p1 = bf16rtn(v.z) | ((unsigned int)bf16rtn(v.w) << 16);
      *(uint2*)(Wf + ((s4 * 4 + wv) * 64 + lane) * 8 + jj) = make_uint2(p0, p1);
    }
    __syncthreads();
#pragma unroll
    for (int s4 = 0; s4 < 4; ++s4) {
      bf16x8 a = *(const bf16x8*)(Wf + ((s4 * 4 + w) * 64 + l) * 8);
      bf16x8 bfr = *(const bf16x8*)(Cf + ((c * 4 + s4) * 64 + l) * 8);
      acc = __builtin_amdgcn_mfma_f32_32x32x16_bf16(a, bfr, acc, 0, 0, 0);
    }
  }

  const int col = l & 31;
  if (col < KK) {
#pragma unroll
    for (int reg = 0; reg < 16; ++reg) {
      const int row = w * 32 + (reg & 3) + 8 * (reg >> 2) + 4 * (l >> 5);
      U[(row0 + row) * KK + col] = acc[reg];
    }
  }
}

// ---------------------------------------------------------------------------
// scores: partial[slice][k][b] = sum_{cd in slice} G[b][cd]*U[cd][k]
// grid 512 (slices of 512 cd), block 128. G and U each read exactly once.
// ---------------------------------------------------------------------------
__global__ __launch_bounds__(128) void scores_k(const float* __restrict__ G,
                                                const float* __restrict__ U,
                                                float* __restrict__ P) {
  __shared__ float Gs[64][68];
  __shared__ float Ut[20][68];

  const int tid = threadIdx.x;
  const int bsub = tid & 31, kg = tid >> 5;
  const size_t s0 = (size_t)blockIdx.x << 9;

  float acc[2][5] = {};

  for (int c0 = 0; c0 < 512; c0 += 64) {
    __syncthreads();
#pragma unroll
    for (int q = 0; q < 8; ++q) {
      int bb = q * 8 + (tid >> 4);
      float4 g4 = *(const float4*)(G + (size_t)bb * (CC * CC) + s0 + c0 +
                                   (tid & 15) * 4);
      *(float4*)&Gs[bb][(tid & 15) * 4] = g4;
    }
#pragma unroll
    for (int e = 0; e < 10; ++e) {
      int f = e * 128 + tid;
      float val = U[(s0 + c0) * KK + f];
      Ut[f % 20][f / 20] = val;
    }
    __syncthreads();
#pragma unroll
    for (int kk4 = 0; kk4 < 16; ++kk4) {
      float4 ga = *(const float4*)&Gs[bsub][kk4 * 4];
      float4 gb2 = *(const float4*)&Gs[bsub + 32][kk4 * 4];
#pragma unroll
      for (int q = 0; q < 5; ++q) {
        float4 c4 = *(const float4*)&Ut[kg * 5 + q][kk4 * 4];
        acc[0][q] = fmaf(ga.x, c4.x, acc[0][q]);
        acc[0][q] = fmaf(ga.y, c4.y, acc[0][q]);
        acc[0][q] = fmaf(ga.z, c4.z, acc[0][q]);
        acc[0][q] = fmaf(ga.w, c4.w, acc[0][q]);
        acc[1][q] = fmaf(gb2.x, c4.x, acc[1][q]);
        acc[1][q] = fmaf(gb2.y, c4.y, acc[1][q]);
        acc[1][q] = fmaf(gb2.z, c4.z, acc[1][q]);
        acc[1][q] = fmaf(gb2.w, c4.w, acc[1][q]);
      }
    }
  }
#pragma unroll
  for (int q = 0; q < 5; ++q) {
    P[(size_t)blockIdx.x * 1280 + (kg * 5 + q) * 64 + bsub] = acc[0][q];
    P[(size_t)blockIdx.x * 1280 + (kg * 5 + q) * 64 + bsub + 32] = acc[1][q];
  }
}

// offs[k] = ||c_k||^2 - 2*dot(gram_b, c_k).  grid 20, block 64.
__global__ void offs_k(const float* __restrict__ C, const float* __restrict__ gb,
                       float* __restrict__ offs) {
  int k = blockIdx.x, t = threadIdx.x;
  float a = 0.f;
  for (int r = t; r < GR; r += 64) {
    float c = C[k * GR + r];
    a += c * c - 2.0f * gb[r] * c;
  }
#pragma unroll
  for (int o = 32; o; o >>= 1) a += __shfl_down(a, o);
  if (t == 0) offs[k] = a;
}

// argmin over k, then concat(x_main, centers[idx]) -> x_fused. grid 64, blk 256.
__global__ __launch_bounds__(256) void argmin_concat_k(
    const float* __restrict__ P, const float* __restrict__ offs,
    const float* __restrict__ xm, const float* __restrict__ C,
    float* __restrict__ xf) {
  const int b = blockIdx.x, t = threadIdx.x;
  __shared__ float vals[20];
  __shared__ int bestIdx;
  if (t < 20) {
    float s = 0.f;
    for (int sl = 0; sl < 512; ++sl) s += P[(size_t)sl * 1280 + t * 64 + b];
    vals[t] = offs[t] - 2.0f * s;
  }
  __syncthreads();
  if (t == 0) {
    float best = vals[0];
    int bi = 0;
    for (int k = 1; k < 20; ++k)
      if (vals[k] < best) { best = vals[k]; bi = k; }
    bestIdx = bi;
  }
  __syncthreads();
  const int bi = bestIdx;
#pragma unroll
  for (int q = 0; q < 4; ++q) {
    const int i = q * 256 + t;
    xf[(size_t)b * 1024 + i] =
        (i < 512) ? xm[(size_t)b * 512 + i] : C[(size_t)bi * 512 + (i - 512)];
  }
}

// ---------------------------------------------------------------------------
// Linear: out = post(act(opt_LN(A) @ W + bias)).  M=64 rows.
// grid (ceil(N/64), 4), block (64,4). ACT: 0 none, 1 relu, 2 gelu, 3 sigmoid.
// ---------------------------------------------------------------------------
template <int ACT, bool LN, bool GATE, bool RES>
__global__ __launch_bounds__(256) void lin_k(
    const float* __restrict__ A, const float* __restrict__ W,
    const float* __restrict__ bias, const float* __restrict__ lng,
    const float* __restrict__ lnb, const float* __restrict__ gate,
    const float* __restrict__ res, float* __restrict__ out, int N, int K) {
  __shared__ float As[16][520];
  const int tx = threadIdx.x, ty = threadIdx.y;
  const int tid = ty * 64 + tx;
  const int n = blockIdx.x * 64 + tx;
  const int r0 = blockIdx.y * 16;
  float acc[4] = {0.f, 0.f, 0.f, 0.f};

  for (int k0 = 0; k0 < K; k0 += 512) {
    const int KT = (K - k0 < 512) ? (K - k0) : 512;
    __syncthreads();
    const int sr = tid >> 4, scq = tid & 15;
    float lsum = 0.f, lss = 0.f;
#pragma unroll
    for (int q = 0; q < 8; ++q) {
      const int c = scq * 4 + q * 64;
      if (c < KT) {
        float4 v = *(const float4*)(A + (size_t)(r0 + sr) * K + k0 + c);
        *(float4*)&As[sr][c] = v;
        if (LN) {
          lsum += v.x + v.y + v.z + v.w;
          lss += v.x * v.x + v.y * v.y + v.z * v.z + v.w * v.w;
        }
      }
    }
    if (LN) {
#pragma unroll
      for (int o = 1; o < 16; o <<= 1) {
        lsum += __shfl_xor(lsum, o);
        lss += __shfl_xor(lss, o);
      }
      const float m = lsum * (1.0f / 512.0f);
      const float inv = rsqrtf(lss * (1.0f / 512.0f) - m * m + 1e-5f);
#pragma unroll
      for (int q = 0; q < 8; ++q) {
        const int c = scq * 4 + q * 64;
        float4 v = *(float4*)&As[sr][c];
        float4 g4 = *(const float4*)(lng + c);
        float4 b4 = *(const float4*)(lnb + c);
        v.x = (v.x - m) * inv * g4.x + b4.x;
        v.y = (v.y - m) * inv * g4.y + b4.y;
        v.z = (v.z - m) * inv * g4.z + b4.z;
        v.w = (v.w - m) * inv * g4.w + b4.w;
        *(float4*)&As[sr][c] = v;
      }
    }
    __syncthreads();
    if (n < N) {
      for (int kk = 0; kk < KT; kk += 4) {
        const float w0 = W[(size_t)(k0 + kk + 0) * N + n];
        const float w1 = W[(size_t)(k0 + kk + 1) * N + n];
        const float w2 = W[(size_t)(k0 + kk + 2) * N + n];
        const float w3 = W[(size_t)(k0 + kk + 3) * N + n];
#pragma unroll
        for (int u = 0; u < 4; ++u) {
          float4 a4 = *(const float4*)&As[ty * 4 + u][kk];
          acc[u] = fmaf(a4.x, w0, acc[u]);
          acc[u] = fmaf(a4.y, w1, acc[u]);
          acc[u] = fmaf(a4.z, w2, acc[u]);
          acc[u] = fmaf(a4.w, w3, acc[u]);
        }
      }
    }
  }
  if (n < N) {
    const float bv = bias[n];
#pragma unroll
    for (int u = 0; u < 4; ++u) {
      const int r = r0 + ty * 4 + u;
      float v = acc[u] + bv;
      if (ACT == 1) v = v > 0.f ? v : 0.f;
      else if (ACT == 2) v = 0.5f * v * (1.0f + erff(v * 0.70710678118654752f));
      else if (ACT == 3) v = 1.0f / (1.0f + expf(-v));
      if (GATE) v *= gate[(size_t)r * N + n];
      if (RES) v += res[(size_t)r * N + n];
      out[(size_t)r * N + n] = v;
    }
  }
}

// ---------------------------------------------------------------------------
extern "C" void kernel_launch(void* const* d_in, const int* in_sizes, int n_in,
                              void* d_out, int out_size, void* d_ws,
                              size_t ws_size, hipStream_t stream) {
  const float* x_embed = (const float*)d_in[0];
  const float* x_image = (const float*)d_in[1];
  const float* attn_w1 = (const float*)d_in[2];
  const float* attn_b1 = (const float*)d_in[3];
  const float* attn_w2 = (const float*)d_in[4];
  const float* attn_b2 = (const float*)d_in[5];
  const float* ln_ff_g = (const float*)d_in[6];
  const float* ln_ff_b = (const float*)d_in[7];
  const float* ff_w1 = (const float*)d_in[8];
  const float* ff_b1 = (const float*)d_in[9];
  const float* ff_w2 = (const float*)d_in[10];
  const float* ff_b2 = (const float*)d_in[11];
  const float* gram_w = (const float*)d_in[12];
  const float* gram_b = (const float*)d_in[13];
  const float* centers = (const float*)d_in[14];
  const float* gm_w = (const float*)d_in[15];
  const float* gm_b = (const float*)d_in[16];
  const float* ln1_g = (const float*)d_in[17];
  const float* ln1_b = (const float*)d_in[18];
  const float* m1_w = (const float*)d_in[19];
  const float* m1_b = (const float*)d_in[20];
  const float* m2_w1 = (const float*)d_in[21];
  const float* m2_b1 = (const float*)d_in[22];
  const float* m2_w2 = (const float*)d_in[23];
  const float* m2_b2 = (const float*)d_in[24];
  const float* out_w = (const float*)d_in[25];
  const float* out_b = (const float*)d_in[26];

  float* ws = (float*)d_ws;
  size_t off = 0;
  auto alloc = [&](size_t nelem) {
    float* p = ws + off;
    off += (nelem + 63) & ~(size_t)63;
    return p;
  };
  float* G = alloc((size_t)BB * CC * CC);   // 67 MB
  float* U = alloc((size_t)CC * CC * KK);   // 21 MB
  float* P = alloc((size_t)512 * 1280);     // 2.6 MB
  float* offs = alloc(64);
  float* h1 = alloc(BB * DD);
  float* x_attn = alloc(BB * DD);
  float* f1 = alloc(BB * 4 * DD);
  float* x_main = alloc(BB * DD);
  float* x_fused = alloc(BB * (DD + GR));
  float* x_h = alloc(BB * DD);
  float* hh = alloc(BB * DD);
  float* h2 = alloc(BB * DD);
  float* h3 = alloc(BB * (DD / 2));

  dim3 blk(64, 4);

  // --- gram branch ---
  offs_k<<<20, 64, 0, stream>>>(centers, gram_b, offs);
  u_mfma<<<2048, 256, 0, stream>>>(gram_w, centers, U);
  hipFuncSetAttribute(reinterpret_cast<const void*>(gram_mfma),
                      hipFuncAttributeMaxDynamicSharedMemorySize, 65536);
  gram_mfma<<<640, 512, 65536, stream>>>(x_image, G);
  scores_k<<<512, 128, 0, stream>>>(G, U, P);

  // --- MLP branch ---
  lin_k<1, false, false, false><<<dim3(8, 4), blk, 0, stream>>>(
      x_embed, attn_w1, attn_b1, nullptr, nullptr, nullptr, nullptr, h1, 512, 512);
  lin_k<3, false, true, false><<<dim3(8, 4), blk, 0, stream>>>(
      h1, attn_w2, attn_b2, nullptr, nullptr, x_embed, nullptr, x_attn, 512, 512);
  lin_k<2, true, false, false><<<dim3(32, 4), blk, 0, stream>>>(
      x_attn, ff_w1, ff_b1, ln_ff_g, ln_ff_b, nullptr, nullptr, f1, 2048, 512);
  lin_k<0, false, false, true><<<dim3(8, 4), blk, 0, stream>>>(
      f1, ff_w2, ff_b2, nullptr, nullptr, nullptr, x_attn, x_main, 512, 2048);

  // --- fuse ---
  argmin_concat_k<<<64, 256, 0, stream>>>(P, offs, x_main, centers, x_fused);
  lin_k<2, false, false, false><<<dim3(8, 4), blk, 0, stream>>>(
      x_fused, gm_w, gm_b, nullptr, nullptr, nullptr, nullptr, x_h, 512, 1024);
  lin_k<2, true, false, true><<<dim3(8, 4), blk, 0, stream>>>(
      x_h, m1_w, m1_b, ln1_g, ln1_b, nullptr, x_h, hh, 512, 512);
  lin_k<2, false, false, false><<<dim3(8, 4), blk, 0, stream>>>(
      hh, m2_w1, m2_b1, nullptr, nullptr, nullptr, nullptr, h2, 512, 512);
  lin_k<2, false, false, false><<<dim3(4, 4), blk, 0, stream>>>(
      h2, m2_w2, m2_b2, nullptr, nullptr, nullptr, nullptr, h3, 256, 512);
  lin_k<0, false, false, false><<<dim3(1, 4), blk, 0, stream>>>(
      h3, out_w, out_b, nullptr, nullptr, nullptr, nullptr, (float*)d_out, 10, 256);
}

// Round 5
// 747.544 us; speedup vs baseline: 1.5229x; 1.4061x over previous
//
#include <hip/hip_runtime.h>
#include <math.h>

#define BB 64
#define CC 512
#define HW 784
#define DD 512
#define GR 512
#define KK 20

typedef __bf16 bf16x8 __attribute__((ext_vector_type(8)));
typedef float f32x16 __attribute__((ext_vector_type(16)));

__device__ inline unsigned short bf16rtn(float f) {
  unsigned int u = __builtin_bit_cast(unsigned int, f);
  unsigned int r = (u + 0x7FFFu + ((u >> 16) & 1u)) >> 16;
  return (unsigned short)r;
}

// ---------------------------------------------------------------------------
// Gram: G[b] = xf[b] @ xf[b]^T / 784, plain bf16 MFMA (RTN).
// 128x128 tiles, upper-tri pairs mirror-stored. grid (10, 64) like R2.
// 512 thr, 64 KB dynamic LDS (2 planes) -> 2 blocks/CU. BK=112.
// ---------------------------------------------------------------------------
__global__ __launch_bounds__(512) void gram_mfma(const float* __restrict__ X,
                                                 float* __restrict__ G) {
  extern __shared__ unsigned short lds[];
  unsigned short* __restrict__ Apl = lds;           // [128][128] (112 used)
  unsigned short* __restrict__ Bpl = lds + 16384;

  const int b = blockIdx.y;
  int lin = blockIdx.x;
  int i = 0;
  while (lin >= 4 - i) { lin -= 4 - i; ++i; }
  const int j = i + lin;  // i <= j
  const bool diag = (i == j);

  const float* __restrict__ xb = X + (size_t)b * (CC * HW);
  const int tid = threadIdx.x;
  const int w = tid >> 6, l = tid & 63;
  const int wr = w >> 1;  // 0..3: 32-row block
  const int wc = w & 1;   // 0..1: 64-col block

  f32x16 acc0 = {};
  f32x16 acc1 = {};

  const int sr = tid >> 2;        // 0..127 staging row
  const int lane4 = tid & 3;

  for (int it = 0; it < 7; ++it) {
    const int k0 = it * 112;
    __syncthreads();
#pragma unroll
    for (int q = 0; q < 7; ++q) {
      const int pos = lane4 + q * 4;          // float4 index 0..27
      const int chunk = pos >> 1;
      const int soff =
          sr * 128 + (((chunk ^ (sr & 7)) << 3) | ((pos & 1) << 2));
#pragma unroll
      for (int pnl = 0; pnl < 2; ++pnl) {
        if (pnl && diag) break;
        const int rowbase = (pnl ? j : i) * 128;
        float4 v =
            *(const float4*)(xb + (size_t)(rowbase + sr) * HW + k0 + pos * 4);
        unsigned int p0 = bf16rtn(v.x) | ((unsigned int)bf16rtn(v.y) << 16);
        unsigned int p1 = bf16rtn(v.z) | ((unsigned int)bf16rtn(v.w) << 16);
        *(uint2*)((pnl ? Bpl : Apl) + soff) = make_uint2(p0, p1);
      }
    }
    __syncthreads();
    const unsigned short* __restrict__ bP = diag ? Apl : Bpl;
#pragma unroll
    for (int ks = 0; ks < 7; ++ks) {
      const int chunk = ks * 2 + (l >> 5);
      const int ar = wr * 32 + (l & 31);
      bf16x8 a = *(const bf16x8*)(Apl + ar * 128 + ((chunk ^ (ar & 7)) << 3));
      const int br0 = wc * 64 + (l & 31);
      const int br1 = br0 + 32;
      bf16x8 b0 = *(const bf16x8*)(bP + br0 * 128 + ((chunk ^ (br0 & 7)) << 3));
      bf16x8 b1 = *(const bf16x8*)(bP + br1 * 128 + ((chunk ^ (br1 & 7)) << 3));
      acc0 = __builtin_amdgcn_mfma_f32_32x32x16_bf16(a, b0, acc0, 0, 0, 0);
      acc1 = __builtin_amdgcn_mfma_f32_32x32x16_bf16(a, b1, acc1, 0, 0, 0);
    }
  }

  const float sc = 1.0f / (float)HW;
  float* __restrict__ gb = G + (size_t)b * (CC * CC);
  const int rowbase = i * 128 + wr * 32 + 4 * (l >> 5);
  const int colbase = j * 128 + wc * 64 + (l & 31);
#pragma unroll
  for (int n = 0; n < 2; ++n) {
    const f32x16 a = n ? acc1 : acc0;
#pragma unroll
    for (int reg = 0; reg < 16; ++reg) {
      const int row = rowbase + (reg & 3) + 8 * (reg >> 2);
      const int col = colbase + n * 32;
      const float v = a[reg] * sc;
      gb[(size_t)row * CC + col] = v;
      if (!diag) gb[(size_t)col * CC + row] = v;
    }
  }
}

// ---------------------------------------------------------------------------
// U kernel v2: U[cd][k] = sum_r W[cd][r]*C[k][r].  BK=32 (128 B per row-visit)
// -> each 128 B line of gram_w read exactly once. grid 1024, block 256.
// ---------------------------------------------------------------------------
__global__ __launch_bounds__(256) void u_kernel2(const float* __restrict__ W,
                                                 const float* __restrict__ C,
                                                 float* __restrict__ U) {
  __shared__ float Ws[256][36];
  __shared__ float Ct[20][36];

  const int tid = threadIdx.x;
  const int rt = tid >> 2, kq = tid & 3;
  const size_t row0 = (size_t)blockIdx.x << 8;

  float acc[4][5] = {};

  for (int k0 = 0; k0 < GR; k0 += 32) {
    __syncthreads();
#pragma unroll
    for (int q = 0; q < 8; ++q) {
      const int row = q * 32 + (tid >> 3);
      const int col = (tid & 7) * 4;
      float4 w4 = *(const float4*)(W + (row0 + row) * GR + k0 + col);
      *(float4*)&Ws[row][col] = w4;
    }
    if (tid < 160) {
      const int k = tid >> 3, pp = tid & 7;
      *(float4*)&Ct[k][pp * 4] = *(const float4*)(C + k * GR + k0 + pp * 4);
    }
    __syncthreads();
#pragma unroll
    for (int kk4 = 0; kk4 < 8; ++kk4) {
      float4 wv[4];
#pragma unroll
      for (int u = 0; u < 4; ++u)
        wv[u] = *(const float4*)&Ws[rt + u * 64][kk4 * 4];
#pragma unroll
      for (int q = 0; q < 5; ++q) {
        float4 c4 = *(const float4*)&Ct[kq * 5 + q][kk4 * 4];
#pragma unroll
        for (int u = 0; u < 4; ++u) {
          acc[u][q] = fmaf(wv[u].x, c4.x, acc[u][q]);
          acc[u][q] = fmaf(wv[u].y, c4.y, acc[u][q]);
          acc[u][q] = fmaf(wv[u].z, c4.z, acc[u][q]);
          acc[u][q] = fmaf(wv[u].w, c4.w, acc[u][q]);
        }
      }
    }
  }
#pragma unroll
  for (int u = 0; u < 4; ++u)
#pragma unroll
    for (int q = 0; q < 5; ++q)
      U[(row0 + rt + u * 64) * KK + kq * 5 + q] = acc[u][q];
}

// ---------------------------------------------------------------------------
// scores: partial[slice][k][b] = sum_{cd in slice} G[b][cd]*U[cd][k]
// grid 512 (slices of 512 cd), block 128.  (identical to R2)
// ---------------------------------------------------------------------------
__global__ __launch_bounds__(128) void scores_k(const float* __restrict__ G,
                                                const float* __restrict__ U,
                                                float* __restrict__ P) {
  __shared__ float Gs[64][68];
  __shared__ float Ut[20][68];

  const int tid = threadIdx.x;
  const int bsub = tid & 31, kg = tid >> 5;
  const size_t s0 = (size_t)blockIdx.x << 9;

  float acc[2][5] = {};

  for (int c0 = 0; c0 < 512; c0 += 64) {
    __syncthreads();
#pragma unroll
    for (int q = 0; q < 8; ++q) {
      int bb = q * 8 + (tid >> 4);
      float4 g4 = *(const float4*)(G + (size_t)bb * (CC * CC) + s0 + c0 +
                                   (tid & 15) * 4);
      *(float4*)&Gs[bb][(tid & 15) * 4] = g4;
    }
#pragma unroll
    for (int e = 0; e < 10; ++e) {
      int f = e * 128 + tid;
      float val = U[(s0 + c0) * KK + f];
      Ut[f % 20][f / 20] = val;
    }
    __syncthreads();
#pragma unroll
    for (int kk4 = 0; kk4 < 16; ++kk4) {
      float4 ga = *(const float4*)&Gs[bsub][kk4 * 4];
      float4 gb2 = *(const float4*)&Gs[bsub + 32][kk4 * 4];
#pragma unroll
      for (int q = 0; q < 5; ++q) {
        float4 c4 = *(const float4*)&Ut[kg * 5 + q][kk4 * 4];
        acc[0][q] = fmaf(ga.x, c4.x, acc[0][q]);
        acc[0][q] = fmaf(ga.y, c4.y, acc[0][q]);
        acc[0][q] = fmaf(ga.z, c4.z, acc[0][q]);
        acc[0][q] = fmaf(ga.w, c4.w, acc[0][q]);
        acc[1][q] = fmaf(gb2.x, c4.x, acc[1][q]);
        acc[1][q] = fmaf(gb2.y, c4.y, acc[1][q]);
        acc[1][q] = fmaf(gb2.z, c4.z, acc[1][q]);
        acc[1][q] = fmaf(gb2.w, c4.w, acc[1][q]);
      }
    }
  }
#pragma unroll
  for (int q = 0; q < 5; ++q) {
    P[(size_t)blockIdx.x * 1280 + (kg * 5 + q) * 64 + bsub] = acc[0][q];
    P[(size_t)blockIdx.x * 1280 + (kg * 5 + q) * 64 + bsub + 32] = acc[1][q];
  }
}

// offs[k] = ||c_k||^2 - 2*dot(gram_b, c_k).  grid 20, block 64.
__global__ void offs_k(const float* __restrict__ C, const float* __restrict__ gb,
                       float* __restrict__ offs) {
  int k = blockIdx.x, t = threadIdx.x;
  float a = 0.f;
  for (int r = t; r < GR; r += 64) {
    float c = C[k * GR + r];
    a += c * c - 2.0f * gb[r] * c;
  }
#pragma unroll
  for (int o = 32; o; o >>= 1) a += __shfl_down(a, o);
  if (t == 0) offs[k] = a;
}

// argmin over k of offs[k] - 2*sum_slices P.  grid 64, block 64. (R2)
__global__ void argmin_k(const float* __restrict__ P,
                         const float* __restrict__ offs,
                         int* __restrict__ idx) {
  int b = blockIdx.x, t = threadIdx.x;
  __shared__ float vals[20];
  if (t < 20) {
    float s = 0.f;
    for (int sl = 0; sl < 512; ++sl) s += P[(size_t)sl * 1280 + t * 64 + b];
    vals[t] = offs[t] - 2.0f * s;
  }
  __syncthreads();
  if (t == 0) {
    float best = vals[0];
    int bi = 0;
    for (int k = 1; k < 20; ++k)
      if (vals[k] < best) { best = vals[k]; bi = k; }
    idx[b] = bi;
  }
}

// x_fused[b] = concat(x_main[b], centers[idx[b]]).  grid 64, block 256. (R2)
__global__ void concat_k(const float* __restrict__ xm,
                         const float* __restrict__ C,
                         const int* __restrict__ idx,
                         float* __restrict__ xf) {
  int b = blockIdx.x, t = threadIdx.x;
  for (int i2 = t; i2 < DD; i2 += 256) xf[b * 1024 + i2] = xm[b * DD + i2];
  int c = idx[b];
  for (int i2 = t; i2 < GR; i2 += 256)
    xf[b * 1024 + DD + i2] = C[c * GR + i2];
}

// Row LayerNorm over 512.  grid 64, block 256. (R2)
__global__ void ln_k(const float* __restrict__ x, const float* __restrict__ g,
                     const float* __restrict__ bt, float* __restrict__ y) {
  int b = blockIdx.x, t = threadIdx.x;
  float2 v = *(const float2*)(x + b * DD + t * 2);
  float s = v.x + v.y;
  float ss = v.x * v.x + v.y * v.y;
#pragma unroll
  for (int o = 32; o; o >>= 1) {
    s += __shfl_down(s, o);
    ss += __shfl_down(ss, o);
  }
  __shared__ float rs[4], rss[4];
  int w = t >> 6;
  if ((t & 63) == 0) { rs[w] = s; rss[w] = ss; }
  __syncthreads();
  s = rs[0] + rs[1] + rs[2] + rs[3];
  ss = rss[0] + rss[1] + rss[2] + rss[3];
  float m = s * (1.0f / DD);
  float var = ss * (1.0f / DD) - m * m;
  float inv = rsqrtf(var + 1e-5f);
  float2 gg = *(const float2*)(g + t * 2);
  float2 bb = *(const float2*)(bt + t * 2);
  float2 o2;
  o2.x = (v.x - m) * inv * gg.x + bb.x;
  o2.y = (v.y - m) * inv * gg.y + bb.y;
  *(float2*)(y + b * DD + t * 2) = o2;
}

// ---------------------------------------------------------------------------
// Generic small GEMM: out = post(act(A@W + bias)).  M=64 rows. (R2)
// grid ((N+63)/64, 4), block (64,4). ACT: 0 none, 1 relu, 2 gelu, 3 sigmoid.
// ---------------------------------------------------------------------------
template <int ACT, bool GATE, bool RES>
__global__ __launch_bounds__(256) void linear_k(
    const float* __restrict__ A, const float* __restrict__ W,
    const float* __restrict__ bias, const float* __restrict__ gate,
    const float* __restrict__ res, float* __restrict__ out, int N, int K) {
  __shared__ float As[16][34];
  const int tx = threadIdx.x, ty = threadIdx.y;
  const int n = blockIdx.x * 64 + tx;
  const int r0 = blockIdx.y * 16;
  float acc[4] = {0.f, 0.f, 0.f, 0.f};
  const int t2 = (ty * 64 + tx) * 2;
  const int srr = t2 >> 5, skk = t2 & 31;

  for (int k0 = 0; k0 < K; k0 += 32) {
    __syncthreads();
    float2 a2 = *(const float2*)(A + (size_t)(r0 + srr) * K + k0 + skk);
    As[srr][skk] = a2.x;
    As[srr][skk + 1] = a2.y;
    __syncthreads();
    if (n < N) {
#pragma unroll
      for (int kk = 0; kk < 32; ++kk) {
        float w = W[(size_t)(k0 + kk) * N + n];
#pragma unroll
        for (int u = 0; u < 4; ++u)
          acc[u] = fmaf(As[ty * 4 + u][kk], w, acc[u]);
      }
    }
  }
  if (n < N) {
    float bv = bias[n];
#pragma unroll
    for (int u = 0; u < 4; ++u) {
      int r = r0 + ty * 4 + u;
      float v = acc[u] + bv;
      if (ACT == 1) v = v > 0.f ? v : 0.f;
      else if (ACT == 2) v = 0.5f * v * (1.0f + erff(v * 0.70710678118654752f));
      else if (ACT == 3) v = 1.0f / (1.0f + expf(-v));
      if (GATE) v *= gate[(size_t)r * N + n];
      if (RES) v += res[(size_t)r * N + n];
      out[(size_t)r * N + n] = v;
    }
  }
}

// ---------------------------------------------------------------------------
extern "C" void kernel_launch(void* const* d_in, const int* in_sizes, int n_in,
                              void* d_out, int out_size, void* d_ws,
                              size_t ws_size, hipStream_t stream) {
  const float* x_embed = (const float*)d_in[0];
  const float* x_image = (const float*)d_in[1];
  const float* attn_w1 = (const float*)d_in[2];
  const float* attn_b1 = (const float*)d_in[3];
  const float* attn_w2 = (const float*)d_in[4];
  const float* attn_b2 = (const float*)d_in[5];
  const float* ln_ff_g = (const float*)d_in[6];
  const float* ln_ff_b = (const float*)d_in[7];
  const float* ff_w1 = (const float*)d_in[8];
  const float* ff_b1 = (const float*)d_in[9];
  const float* ff_w2 = (const float*)d_in[10];
  const float* ff_b2 = (const float*)d_in[11];
  const float* gram_w = (const float*)d_in[12];
  const float* gram_b = (const float*)d_in[13];
  const float* centers = (const float*)d_in[14];
  const float* gm_w = (const float*)d_in[15];
  const float* gm_b = (const float*)d_in[16];
  const float* ln1_g = (const float*)d_in[17];
  const float* ln1_b = (const float*)d_in[18];
  const float* m1_w = (const float*)d_in[19];
  const float* m1_b = (const float*)d_in[20];
  const float* m2_w1 = (const float*)d_in[21];
  const float* m2_b1 = (const float*)d_in[22];
  const float* m2_w2 = (const float*)d_in[23];
  const float* m2_b2 = (const float*)d_in[24];
  const float* out_w = (const float*)d_in[25];
  const float* out_b = (const float*)d_in[26];

  float* ws = (float*)d_ws;
  size_t off = 0;
  auto alloc = [&](size_t nelem) {
    float* p = ws + off;
    off += (nelem + 63) & ~(size_t)63;
    return p;
  };
  float* G = alloc((size_t)BB * CC * CC);   // 67 MB
  float* U = alloc((size_t)CC * CC * KK);   // 21 MB
  float* P = alloc((size_t)512 * 1280);     // 2.6 MB
  float* offs = alloc(64);
  int* idx = (int*)alloc(64);
  float* h1 = alloc(BB * DD);
  float* x_attn = alloc(BB * DD);
  float* xln = alloc(BB * DD);
  float* f1 = alloc(BB * 4 * DD);
  float* x_main = alloc(BB * DD);
  float* x_fused = alloc(BB * (DD + GR));
  float* x_h = alloc(BB * DD);
  float* xln1 = alloc(BB * DD);
  float* hh = alloc(BB * DD);
  float* h2 = alloc(BB * DD);
  float* h3 = alloc(BB * (DD / 2));

  // --- Gram branch ---
  hipFuncSetAttribute(reinterpret_cast<const void*>(gram_mfma),
                      hipFuncAttributeMaxDynamicSharedMemorySize, 65536);
  gram_mfma<<<dim3(10, BB), 512, 65536, stream>>>(x_image, G);
  u_kernel2<<<1024, 256, 0, stream>>>(gram_w, centers, U);
  scores_k<<<512, 128, 0, stream>>>(G, U, P);
  offs_k<<<20, 64, 0, stream>>>(centers, gram_b, offs);
  argmin_k<<<64, 64, 0, stream>>>(P, offs, idx);

  // --- MLP branch ---
  dim3 blk(64, 4);
  linear_k<1, false, false><<<dim3(8, 4), blk, 0, stream>>>(
      x_embed, attn_w1, attn_b1, nullptr, nullptr, h1, 512, 512);
  linear_k<3, true, false><<<dim3(8, 4), blk, 0, stream>>>(
      h1, attn_w2, attn_b2, x_embed, nullptr, x_attn, 512, 512);
  ln_k<<<64, 256, 0, stream>>>(x_attn, ln_ff_g, ln_ff_b, xln);
  linear_k<2, false, false><<<dim3(32, 4), blk, 0, stream>>>(
      xln, ff_w1, ff_b1, nullptr, nullptr, f1, 2048, 512);
  linear_k<0, false, true><<<dim3(8, 4), blk, 0, stream>>>(
      f1, ff_w2, ff_b2, nullptr, x_attn, x_main, 512, 2048);

  // --- fuse ---
  concat_k<<<64, 256, 0, stream>>>(x_main, centers, idx, x_fused);
  linear_k<2, false, false><<<dim3(8, 4), blk, 0, stream>>>(
      x_fused, gm_w, gm_b, nullptr, nullptr, x_h, 512, 1024);
  ln_k<<<64, 256, 0, stream>>>(x_h, ln1_g, ln1_b, xln1);
  linear_k<2, false, true><<<dim3(8, 4), blk, 0, stream>>>(
      xln1, m1_w, m1_b, nullptr, x_h, hh, 512, 512);
  linear_k<2, false, false><<<dim3(8, 4), blk, 0, stream>>>(
      hh, m2_w1, m2_b1, nullptr, nullptr, h2, 512, 512);
  linear_k<2, false, false><<<dim3(4, 4), blk, 0, stream>>>(
      h2, m2_w2, m2_b2, nullptr, nullptr, h3, 256, 512);
  linear_k<0, false, false><<<dim3(1, 4), blk, 0, stream>>>(
      h3, out_w, out_b, nullptr, nullptr, (float*)d_out, 10, 256);
}